// Round 6
// baseline (812.719 us; speedup 1.0000x reference)
//
#include <hip/hip_runtime.h>

// Problem constants (reference: B,M,N,L,S,KERN = 4,256,256,24,22,256; KERN==M → tile is identity)
constexpr int B_ = 4, M_ = 256, N_ = 256, L_ = 24, S_ = 22;
constexpr int NY = 280;   // 279 dispersion columns, padded to 280

// Color bases as COMPILE-TIME constants: F_c[l] = exp(-0.5*((wl-mu_c)/50)^2),
// wl = 400 + 300*l/23, pairing per reference: wr<->620, wg<->550, wb<->450, wc<->500.
// (Baking literals kills the per-use LDS broadcast reads of the F table.)
constexpr float FR[L_] = {  // mu = 620
    6.252150e-05f, 1.904358e-04f, 5.418690e-04f, 1.440515e-03f, 3.577400e-03f,
    8.299750e-03f, 1.798893e-02f, 3.642490e-02f, 6.890060e-02f, 1.217600e-01f,
    2.010120e-01f, 3.100190e-01f, 4.466857e-01f, 6.012587e-01f, 7.560710e-01f,
    8.881955e-01f, 9.747661e-01f, 9.993953e-01f, 9.572367e-01f, 8.565352e-01f,
    7.160078e-01f, 5.591580e-01f, 4.079402e-01f, 2.780373e-01f};
constexpr float FG[L_] = {  // mu = 550
    1.110900e-02f, 2.348440e-02f, 4.638000e-02f, 8.557090e-02f, 1.474900e-01f,
    2.374920e-01f, 3.572560e-01f, 5.020580e-01f, 6.591400e-01f, 8.084270e-01f,
    9.262975e-01f, 9.915296e-01f, 9.915296e-01f, 9.262975e-01f, 8.084270e-01f,
    6.591400e-01f, 5.020580e-01f, 3.572560e-01f, 2.374920e-01f, 1.474900e-01f,
    8.557090e-02f, 4.638000e-02f, 2.348440e-02f, 1.110900e-02f};
constexpr float FB[L_] = {  // mu = 450 (pairs with wb)
    6.065307e-01f, 7.609727e-01f, 8.919300e-01f, 9.766475e-01f, 9.990553e-01f,
    9.547420e-01f, 8.523698e-01f, 7.109096e-01f, 5.539184e-01f, 4.032022e-01f,
    2.741855e-01f, 1.741852e-01f, 1.033776e-01f, 5.731640e-02f, 2.968800e-02f,
    1.436580e-02f, 6.494090e-03f, 2.742560e-03f, 1.079230e-03f, 3.988070e-04f,
    1.369660e-04f, 4.417250e-05f, 1.327420e-05f, 3.726650e-06f};
constexpr float FC[L_] = {  // mu = 500 (pairs with wc)
    1.353353e-01f, 2.204053e-01f, 3.353338e-01f, 4.766271e-01f, 6.328849e-01f,
    7.850828e-01f, 9.098110e-01f, 9.849909e-01f, 9.962264e-01f, 9.413024e-01f,
    8.308921e-01f, 6.851808e-01f, 5.278508e-01f, 3.798934e-01f, 2.554222e-01f,
    1.604349e-01f, 9.414200e-02f, 5.160780e-02f, 2.642960e-02f, 1.264440e-02f,
    5.651680e-03f, 2.359870e-03f, 9.205430e-04f, 3.354630e-04f};

// R5 post-mortem: five kernels, one invariant 725-733us. The invariant was
// >=90 floats of per-thread ARRAY state with VGPR_Count stuck at 64-88: the
// arrays lived in scratch every round (~2.5 GB scratch traffic/launch,
// latency-bound). R6 makes per-thread arrays structurally impossible:
//   xv[]   -> planar LDS xl[l][t]  (lane-consecutive, conflict-free)
//   Xacc[] -> planar LDS Xl[l][t]  (RMW, no contention)
//   G0/G1  -> recomputed in phase B (8 FMA, VALU was 4% busy)
//   F table-> compile-time literals (no LDS broadcast reads)
// Only live state: 8 named a-scalars + temps (~40 VGPRs).
__global__ __launch_bounds__(256) void cassi_fused(
    const float* __restrict__ x,
    const float* __restrict__ wr, const float* __restrict__ wg,
    const float* __restrict__ wb, const float* __restrict__ wc,
    float* __restrict__ out, float* __restrict__ bmax_out)
{
    __shared__ float xl[L_ * 256];   // [l][t] planar, 24.5 KB
    __shared__ float Xl[L_ * 256];   // [l][t] planar, 24.5 KB
    __shared__ float Y[2][2][NY];    // [iter parity][s in pair][n'], 4.5 KB
    __shared__ float wmax[4];

    const int t = threadIdx.x;
    const int b = blockIdx.x & (B_ - 1);
    const int m = blockIdx.x >> 2;

    // Stage x row (6 aligned float4 loads) into planar LDS; zero X accumulator.
    {
        const float4* x4 = reinterpret_cast<const float4*>(x + ((b * M_ + m) * N_ + t) * L_);
        #pragma unroll
        for (int i = 0; i < L_ / 4; ++i) {
            const float4 v = x4[i];
            xl[(4 * i + 0) * 256 + t] = v.x;
            xl[(4 * i + 1) * 256 + t] = v.y;
            xl[(4 * i + 2) * 256 + t] = v.z;
            xl[(4 * i + 3) * 256 + t] = v.w;
        }
        #pragma unroll
        for (int l = 0; l < L_; ++l) Xl[l * 256 + t] = 0.f;
    }

    const int wbase = (m * N_ + t) * S_;   // thread's weight chunk (22 floats, 8B-aligned)

    #pragma unroll 1
    for (int i = 0; i < S_ / 2; ++i) {     // s = 2i, 2i+1
        float* __restrict__ Y0 = Y[i & 1][0];
        float* __restrict__ Y1 = Y[i & 1][1];

        // zero this iteration's slices (parity double-buffer; safe: barrier analysis in R5)
        Y0[t] = 0.f; Y1[t] = 0.f;
        if (t < NY - 256) { Y0[256 + t] = 0.f; Y1[256 + t] = 0.f; }

        // normalized weights for s, s+1 — 8 NAMED scalars, no arrays
        const float2 r = *reinterpret_cast<const float2*>(wr + wbase + 2 * i);
        const float2 g = *reinterpret_cast<const float2*>(wg + wbase + 2 * i);
        const float2 u = *reinterpret_cast<const float2*>(wb + wbase + 2 * i);
        const float2 v = *reinterpret_cast<const float2*>(wc + wbase + 2 * i);
        const float i0 = 1.f / (r.x + g.x + u.x + v.x);
        const float i1 = 1.f / (r.y + g.y + u.y + v.y);
        const float a00 = r.x * i0, a10 = g.x * i0, a20 = u.x * i0, a30 = v.x * i0;
        const float a01 = r.y * i1, a11 = g.y * i1, a21 = u.y * i1, a31 = v.y * i1;

        __syncthreads();   // zeros + (iter 0) x staging visible

        // Phase A: scatter. Within one l all lanes hit distinct addresses;
        // cross-l collisions between waves are resolved by ds_add atomics.
        #pragma unroll
        for (int l = 0; l < L_; ++l) {
            const float xv = xl[l * 256 + t];
            const float G0 = a00 * FR[l] + a10 * FG[l] + a20 * FB[l] + a30 * FC[l];
            const float G1 = a01 * FR[l] + a11 * FG[l] + a21 * FB[l] + a31 * FC[l];
            atomicAdd(&Y0[t + l], G0 * xv);
            atomicAdd(&Y1[t + l], G1 * xv);
        }

        __syncthreads();   // Y complete for s, s+1

        // Phase B: gather; accumulate into LDS X (G recomputed — 8 FMA).
        #pragma unroll
        for (int l = 0; l < L_; ++l) {
            const float G0 = a00 * FR[l] + a10 * FG[l] + a20 * FB[l] + a30 * FC[l];
            const float G1 = a01 * FR[l] + a11 * FG[l] + a21 * FB[l] + a31 * FC[l];
            Xl[l * 256 + t] += G0 * Y0[t + l] + G1 * Y1[t + l];
        }
    }

    // Epilogue: each thread reads back ONLY its own Xl entries (no race, no
    // barrier needed), stores unnormalized row, tracks per-block max.
    float vmax = 0.f;
    float4* o4 = reinterpret_cast<float4*>(out + ((b * M_ + m) * N_ + t) * L_);
    #pragma unroll
    for (int i = 0; i < L_ / 4; ++i) {
        float4 vq;
        vq.x = Xl[(4 * i + 0) * 256 + t];
        vq.y = Xl[(4 * i + 1) * 256 + t];
        vq.z = Xl[(4 * i + 2) * 256 + t];
        vq.w = Xl[(4 * i + 3) * 256 + t];
        vmax = fmaxf(vmax, fmaxf(fmaxf(vq.x, vq.y), fmaxf(vq.z, vq.w)));
        o4[i] = vq;
    }

    #pragma unroll
    for (int off = 32; off > 0; off >>= 1)
        vmax = fmaxf(vmax, __shfl_xor(vmax, off, 64));
    if ((t & 63) == 0) wmax[t >> 6] = vmax;
    __syncthreads();
    if (t == 0)
        bmax_out[blockIdx.x] = fmaxf(fmaxf(wmax[0], wmax[1]), fmaxf(wmax[2], wmax[3]));
}

// One block: reduce the 1024 per-block maxes to the scalar at gmax.
__global__ __launch_bounds__(256) void cassi_reduce_max(const float* __restrict__ bmax,
                                                        float* __restrict__ gmax)
{
    __shared__ float wm[4];
    const int t = threadIdx.x;
    float v = fmaxf(fmaxf(bmax[t], bmax[t + 256]),
                    fmaxf(bmax[t + 512], bmax[t + 768]));
    #pragma unroll
    for (int off = 32; off > 0; off >>= 1)
        v = fmaxf(v, __shfl_xor(v, off, 64));
    if ((t & 63) == 0) wm[t >> 6] = v;
    __syncthreads();
    if (t == 0) *gmax = fmaxf(fmaxf(wm[0], wm[1]), fmaxf(wm[2], wm[3]));
}

__global__ __launch_bounds__(256) void cassi_norm(float* __restrict__ out,
                                                  const float* __restrict__ gmax)
{
    const float inv = 1.f / *gmax;
    const int i = (blockIdx.x * 256 + threadIdx.x) * 4;
    float4 v = *reinterpret_cast<float4*>(out + i);
    v.x *= inv; v.y *= inv; v.z *= inv; v.w *= inv;
    *reinterpret_cast<float4*>(out + i) = v;
}

extern "C" void kernel_launch(void* const* d_in, const int* in_sizes, int n_in,
                              void* d_out, int out_size, void* d_ws, size_t ws_size,
                              hipStream_t stream) {
    const float* x  = (const float*)d_in[0];
    const float* wr = (const float*)d_in[1];
    const float* wg = (const float*)d_in[2];
    const float* wb = (const float*)d_in[3];
    const float* wc = (const float*)d_in[4];
    float* out  = (float*)d_out;
    float* bmax = (float*)d_ws;          // 1024 per-block maxes
    float* gmax = bmax + 1024;           // final scalar

    cassi_fused<<<B_ * M_, 256, 0, stream>>>(x, wr, wg, wb, wc, out, bmax);
    cassi_reduce_max<<<1, 256, 0, stream>>>(bmax, gmax);
    const int n4blocks = (B_ * M_ * N_ * L_) / 4 / 256;     // 6144, exact
    cassi_norm<<<n4blocks, 256, 0, stream>>>(out, gmax);
}

// Round 8
// 229.180 us; speedup vs baseline: 3.5462x; 3.5462x over previous
//
#include <hip/hip_runtime.h>

// Problem constants (reference: B,M,N,L,S,KERN = 4,256,256,24,22,256; KERN==M → tile is identity)
constexpr int B_ = 4, M_ = 256, N_ = 256, L_ = 24, S_ = 22;
constexpr int NS_ = N_ * S_;      // 5632 floats per (m) row per weight array
constexpr int AP_ = 257;          // a4 row pitch (float4 units), +1 pad
constexpr int YP_ = 280;          // Y row pitch (floats), holds 279 columns

// Color bases as COMPILE-TIME constants (validated by R6 pass):
// F_c[l] = exp(-0.5*((400+300*l/23 - mu_c)/50)^2); pairing wr<->620, wg<->550, wb<->450, wc<->500.
constexpr float FR[L_] = {  // mu = 620
    6.252150e-05f, 1.904358e-04f, 5.418690e-04f, 1.440515e-03f, 3.577400e-03f,
    8.299750e-03f, 1.798893e-02f, 3.642490e-02f, 6.890060e-02f, 1.217600e-01f,
    2.010120e-01f, 3.100190e-01f, 4.466857e-01f, 6.012587e-01f, 7.560710e-01f,
    8.881955e-01f, 9.747661e-01f, 9.993953e-01f, 9.572367e-01f, 8.565352e-01f,
    7.160078e-01f, 5.591580e-01f, 4.079402e-01f, 2.780373e-01f};
constexpr float FG[L_] = {  // mu = 550
    1.110900e-02f, 2.348440e-02f, 4.638000e-02f, 8.557090e-02f, 1.474900e-01f,
    2.374920e-01f, 3.572560e-01f, 5.020580e-01f, 6.591400e-01f, 8.084270e-01f,
    9.262975e-01f, 9.915296e-01f, 9.915296e-01f, 9.262975e-01f, 8.084270e-01f,
    6.591400e-01f, 5.020580e-01f, 3.572560e-01f, 2.374920e-01f, 1.474900e-01f,
    8.557090e-02f, 4.638000e-02f, 2.348440e-02f, 1.110900e-02f};
constexpr float FB[L_] = {  // mu = 450 (pairs with wb)
    6.065307e-01f, 7.609727e-01f, 8.919300e-01f, 9.766475e-01f, 9.990553e-01f,
    9.547420e-01f, 8.523698e-01f, 7.109096e-01f, 5.539184e-01f, 4.032022e-01f,
    2.741855e-01f, 1.741852e-01f, 1.033776e-01f, 5.731640e-02f, 2.968800e-02f,
    1.436580e-02f, 6.494090e-03f, 2.742560e-03f, 1.079230e-03f, 3.988070e-04f,
    1.369660e-04f, 4.417250e-05f, 1.327420e-05f, 3.726650e-06f};
constexpr float FC[L_] = {  // mu = 500 (pairs with wc)
    1.353353e-01f, 2.204053e-01f, 3.353338e-01f, 4.766271e-01f, 6.328849e-01f,
    7.850828e-01f, 9.098110e-01f, 9.849909e-01f, 9.962264e-01f, 9.413024e-01f,
    8.308921e-01f, 6.851808e-01f, 5.278508e-01f, 3.798934e-01f, 2.554222e-01f,
    1.604349e-01f, 9.414200e-02f, 5.160780e-02f, 2.642960e-02f, 1.264440e-02f,
    5.651680e-03f, 2.359870e-03f, 9.205430e-04f, 3.354630e-04f};

// Dynamic LDS layout (floats):
//   xT [24][256]           6144 floats   x transposed planar [l][n]
//   a4 [22][257] float4   22616 floats   normalized weights, c-packed, +1 row pad
//   Y  [22][280]           6160 floats   dispersed plane [s][n']
constexpr int XT_OFF = 0;
constexpr int A4_OFF = 6144;                 // float index (16B-aligned: 24576 B)
constexpr int Y_OFF  = A4_OFF + 4 * (S_ * AP_);  // 6144 + 22616 = 28760
constexpr int LDS_FLOATS = Y_OFF + S_ * YP_;     // 34920 floats = 139680 B
constexpr int LDS_BYTES = LDS_FLOATS * 4;

// R6 post-mortem: 729us with PROVABLY zero scratch (WRITE_SIZE == output),
// zero conflicts, zero global atomics, VALU 3%. Six rounds, one duration.
// Remaining never-changed suspects: LDS atomics (528/thread), 11x-repeated
// 88B-strided weight gathers, barrier-per-s loop. R7 removes ALL three:
// gather formulation (each Y[n',s] assigned once - no atomics, no zeroing),
// weights staged ONCE coalesced into LDS (normalized float4), 2 barriers.
// (R7 never ran: GPU acquisition timeout. Identical resubmission.)
__global__ __launch_bounds__(256) void cassi_fused(
    const float* __restrict__ x,
    const float* __restrict__ wr, const float* __restrict__ wg,
    const float* __restrict__ wb, const float* __restrict__ wc,
    float* __restrict__ out, float* __restrict__ bmax_out)
{
    extern __shared__ float lds[];
    float*  xT = lds + XT_OFF;
    float4* a4 = reinterpret_cast<float4*>(lds + A4_OFF);
    float*  Y  = lds + Y_OFF;
    __shared__ float wmax[4];

    const int t = threadIdx.x;
    const int b = blockIdx.x & (B_ - 1);
    const int m = blockIdx.x >> 2;

    // ---- Staging (all coalesced, done ONCE) ----
    // x row t: 96 B contiguous -> planar xT[l][t]
    {
        const float4* x4 = reinterpret_cast<const float4*>(x + ((b * M_ + m) * N_ + t) * L_);
        #pragma unroll
        for (int i = 0; i < L_ / 4; ++i) {
            const float4 v = x4[i];
            xT[(4 * i + 0) * 256 + t] = v.x;
            xT[(4 * i + 1) * 256 + t] = v.y;
            xT[(4 * i + 2) * 256 + t] = v.z;
            xT[(4 * i + 3) * 256 + t] = v.w;
        }
    }
    // weights: flat coalesced b32 reads over the m-row (5632 floats/array),
    // normalize, pack c into float4, store a4[s][n] (pitch 257).
    {
        const float* wrm = wr + m * NS_;
        const float* wgm = wg + m * NS_;
        const float* wbm = wb + m * NS_;
        const float* wcm = wc + m * NS_;
        #pragma unroll 1
        for (int i = 0; i < S_; ++i) {      // 22 * 256 = 5632 = NS_
            const int f = i * 256 + t;
            const float r = wrm[f], g = wgm[f], u = wbm[f], v = wcm[f];
            const int n = f / S_, s = f - n * S_;
            const float inv = 1.f / (r + g + u + v);
            float4 p; p.x = r * inv; p.y = g * inv; p.z = u * inv; p.w = v * inv;
            a4[s * AP_ + n] = p;
        }
    }
    __syncthreads();

    // ---- Phase A: GATHER.  Y[s][n'] = sum_l G(n'-l,l,s) * x[n'-l, l].
    // Lane t computes n'=t; lanes t<23 ALSO cover tail n'=256+t using the
    // complementarity trick: at each l exactly one of {main: l<=t, tail: l>t}
    // is valid, so one LDS read-set serves both (zero extra instructions).
    #pragma unroll 1
    for (int i = 0; i < S_ / 2; ++i) {
        const int s0 = 2 * i;
        float aM0 = 0.f, aM1 = 0.f, aT0 = 0.f, aT1 = 0.f;
        #pragma unroll
        for (int l = 0; l < L_; ++l) {
            const bool mn = (l <= t);
            const int idx = mn ? (t - l) : (256 + t - l);   // always in [0,255]/[233,255]
            const float  xv = xT[l * 256 + idx];
            const float4 p  = a4[s0 * AP_ + idx];
            const float4 q  = a4[(s0 + 1) * AP_ + idx];
            const float G0 = p.x * FR[l] + p.y * FG[l] + p.z * FB[l] + p.w * FC[l];
            const float G1 = q.x * FR[l] + q.y * FG[l] + q.z * FB[l] + q.w * FC[l];
            const float c0 = G0 * xv, c1 = G1 * xv;
            aM0 += mn ? c0 : 0.f;   aM1 += mn ? c1 : 0.f;
            aT0 += mn ? 0.f : c0;   aT1 += mn ? 0.f : c1;
        }
        Y[s0 * YP_ + t] = aM0;
        Y[(s0 + 1) * YP_ + t] = aM1;
        if (t < N_ + L_ - 1 - 256) {        // t < 23: tail columns 256..278
            Y[s0 * YP_ + 256 + t] = aT0;
            Y[(s0 + 1) * YP_ + 256 + t] = aT1;
        }
    }
    __syncthreads();

    // ---- Phase B: X[n,l] = sum_c F_c[l] * sum_s a_c[n,s] * Y[s][n+l].
    // l in quads; the c-sum is deferred outside the s-loop (rank-4 trick).
    float vmax = 0.f;
    float4* o4 = reinterpret_cast<float4*>(out + ((b * M_ + m) * N_ + t) * L_);
    #pragma unroll 1
    for (int lq = 0; lq < L_ / 4; ++lq) {
        const int l0 = 4 * lq;
        float4 A0, A1, A2, A3;
        A0.x = A0.y = A0.z = A0.w = 0.f; A1 = A0; A2 = A0; A3 = A0;
        #pragma unroll
        for (int s = 0; s < S_; ++s) {
            const float4 av = a4[s * AP_ + t];
            const float y0 = Y[s * YP_ + t + l0 + 0];
            const float y1 = Y[s * YP_ + t + l0 + 1];
            const float y2 = Y[s * YP_ + t + l0 + 2];
            const float y3 = Y[s * YP_ + t + l0 + 3];
            A0.x += av.x * y0; A0.y += av.y * y0; A0.z += av.z * y0; A0.w += av.w * y0;
            A1.x += av.x * y1; A1.y += av.y * y1; A1.z += av.z * y1; A1.w += av.w * y1;
            A2.x += av.x * y2; A2.y += av.y * y2; A2.z += av.z * y2; A2.w += av.w * y2;
            A3.x += av.x * y3; A3.y += av.y * y3; A3.z += av.z * y3; A3.w += av.w * y3;
        }
        float4 vq;
        vq.x = A0.x * FR[l0+0] + A0.y * FG[l0+0] + A0.z * FB[l0+0] + A0.w * FC[l0+0];
        vq.y = A1.x * FR[l0+1] + A1.y * FG[l0+1] + A1.z * FB[l0+1] + A1.w * FC[l0+1];
        vq.z = A2.x * FR[l0+2] + A2.y * FG[l0+2] + A2.z * FB[l0+2] + A2.w * FC[l0+2];
        vq.w = A3.x * FR[l0+3] + A3.y * FG[l0+3] + A3.z * FB[l0+3] + A3.w * FC[l0+3];
        vmax = fmaxf(vmax, fmaxf(fmaxf(vq.x, vq.y), fmaxf(vq.z, vq.w)));
        o4[lq] = vq;
    }

    // per-block max (plain store; 1-block reduce kernel finishes it)
    #pragma unroll
    for (int off = 32; off > 0; off >>= 1)
        vmax = fmaxf(vmax, __shfl_xor(vmax, off, 64));
    if ((t & 63) == 0) wmax[t >> 6] = vmax;
    __syncthreads();
    if (t == 0)
        bmax_out[blockIdx.x] = fmaxf(fmaxf(wmax[0], wmax[1]), fmaxf(wmax[2], wmax[3]));
}

// One block: reduce the 1024 per-block maxes to the scalar at gmax.
__global__ __launch_bounds__(256) void cassi_reduce_max(const float* __restrict__ bmax,
                                                        float* __restrict__ gmax)
{
    __shared__ float wm[4];
    const int t = threadIdx.x;
    float v = fmaxf(fmaxf(bmax[t], bmax[t + 256]),
                    fmaxf(bmax[t + 512], bmax[t + 768]));
    #pragma unroll
    for (int off = 32; off > 0; off >>= 1)
        v = fmaxf(v, __shfl_xor(v, off, 64));
    if ((t & 63) == 0) wm[t >> 6] = v;
    __syncthreads();
    if (t == 0) *gmax = fmaxf(fmaxf(wm[0], wm[1]), fmaxf(wm[2], wm[3]));
}

__global__ __launch_bounds__(256) void cassi_norm(float* __restrict__ out,
                                                  const float* __restrict__ gmax)
{
    const float inv = 1.f / *gmax;
    const int i = (blockIdx.x * 256 + threadIdx.x) * 4;
    float4 v = *reinterpret_cast<float4*>(out + i);
    v.x *= inv; v.y *= inv; v.z *= inv; v.w *= inv;
    *reinterpret_cast<float4*>(out + i) = v;
}

extern "C" void kernel_launch(void* const* d_in, const int* in_sizes, int n_in,
                              void* d_out, int out_size, void* d_ws, size_t ws_size,
                              hipStream_t stream) {
    const float* x  = (const float*)d_in[0];
    const float* wr = (const float*)d_in[1];
    const float* wg = (const float*)d_in[2];
    const float* wb = (const float*)d_in[3];
    const float* wc = (const float*)d_in[4];
    float* out  = (float*)d_out;
    float* bmax = (float*)d_ws;          // 1024 per-block maxes
    float* gmax = bmax + 1024;           // final scalar

    // >64KB dynamic LDS opt-in (idempotent host-side call; not a stream op)
    hipFuncSetAttribute((const void*)cassi_fused,
                        hipFuncAttributeMaxDynamicSharedMemorySize, LDS_BYTES);

    cassi_fused<<<B_ * M_, 256, LDS_BYTES, stream>>>(x, wr, wg, wb, wc, out, bmax);
    cassi_reduce_max<<<1, 256, 0, stream>>>(bmax, gmax);
    const int n4blocks = (B_ * M_ * N_ * L_) / 4 / 256;     // 6144, exact
    cassi_norm<<<n4blocks, 256, 0, stream>>>(out, gmax);
}

// Round 9
// 167.159 us; speedup vs baseline: 4.8620x; 1.3710x over previous
//
#include <hip/hip_runtime.h>

typedef _Float16 h4 __attribute__((ext_vector_type(4)));
typedef _Float16 h2 __attribute__((ext_vector_type(2)));

// Problem constants (reference: B,M,N,L,S,KERN = 4,256,256,24,22,256; KERN==M → tile is identity)
constexpr int B_ = 4, M_ = 256, N_ = 256, L_ = 24, S_ = 22;
constexpr int SP_  = 24;    // shots padded to 24 (2 zero rows) for clean s-quads
constexpr int AP_  = 257;   // a4h row pitch in h4 units (odd pad)
constexpr int XP_  = 25;    // xT row pitch in halves (50 B rows: odd-ish stride, u16 access)
constexpr int YPH_ = 28;    // Y row pitch in halves (56 B = 14 dwords: b64 reads at minimal 4-deep)
constexpr int NYR_ = 280;   // Y rows per b (279 used)

// Dynamic LDS layout (bytes):
constexpr int A4_BYTES = SP_ * AP_ * 8;        // 49,344
constexpr int XT_BYTES = B_ * N_ * XP_ * 2;    // 51,200
constexpr int Y_BYTES  = B_ * NYR_ * YPH_ * 2; // 62,720
constexpr int WMAX_OFF = A4_BYTES + XT_BYTES + Y_BYTES;  // 163,264 (16B-aligned)
constexpr int LDS_BYTES = WMAX_OFF + 16;                 // 163,280 <= 163,840
constexpr int XT_OFF_H  = A4_BYTES / 2;                  // half-index 24,672
constexpr int Y_OFF_H4  = (A4_BYTES + XT_BYTES) / 8;     // h4-index 12,568 (byte 100,544, 8-aligned)

// Color bases as COMPILE-TIME constants (validated by R6/R8 passes):
// F_c[l] = exp(-0.5*((400+300*l/23 - mu_c)/50)^2); pairing wr<->620, wg<->550, wb<->450, wc<->500.
constexpr float FR[L_] = {  // mu = 620
    6.252150e-05f, 1.904358e-04f, 5.418690e-04f, 1.440515e-03f, 3.577400e-03f,
    8.299750e-03f, 1.798893e-02f, 3.642490e-02f, 6.890060e-02f, 1.217600e-01f,
    2.010120e-01f, 3.100190e-01f, 4.466857e-01f, 6.012587e-01f, 7.560710e-01f,
    8.881955e-01f, 9.747661e-01f, 9.993953e-01f, 9.572367e-01f, 8.565352e-01f,
    7.160078e-01f, 5.591580e-01f, 4.079402e-01f, 2.780373e-01f};
constexpr float FG[L_] = {  // mu = 550
    1.110900e-02f, 2.348440e-02f, 4.638000e-02f, 8.557090e-02f, 1.474900e-01f,
    2.374920e-01f, 3.572560e-01f, 5.020580e-01f, 6.591400e-01f, 8.084270e-01f,
    9.262975e-01f, 9.915296e-01f, 9.915296e-01f, 9.262975e-01f, 8.084270e-01f,
    6.591400e-01f, 5.020580e-01f, 3.572560e-01f, 2.374920e-01f, 1.474900e-01f,
    8.557090e-02f, 4.638000e-02f, 2.348440e-02f, 1.110900e-02f};
constexpr float FB[L_] = {  // mu = 450 (pairs with wb)
    6.065307e-01f, 7.609727e-01f, 8.919300e-01f, 9.766475e-01f, 9.990553e-01f,
    9.547420e-01f, 8.523698e-01f, 7.109096e-01f, 5.539184e-01f, 4.032022e-01f,
    2.741855e-01f, 1.741852e-01f, 1.033776e-01f, 5.731640e-02f, 2.968800e-02f,
    1.436580e-02f, 6.494090e-03f, 2.742560e-03f, 1.079230e-03f, 3.988070e-04f,
    1.369660e-04f, 4.417250e-05f, 1.327420e-05f, 3.726650e-06f};
constexpr float FC[L_] = {  // mu = 500 (pairs with wc)
    1.353353e-01f, 2.204053e-01f, 3.353338e-01f, 4.766271e-01f, 6.328849e-01f,
    7.850828e-01f, 9.098110e-01f, 9.849909e-01f, 9.962264e-01f, 9.413024e-01f,
    8.308921e-01f, 6.851808e-01f, 5.278508e-01f, 3.798934e-01f, 2.554222e-01f,
    1.604349e-01f, 9.414200e-02f, 5.160780e-02f, 2.642960e-02f, 1.264440e-02f,
    5.651680e-03f, 2.359870e-03f, 9.205430e-04f, 3.354630e-04f};

// R8 post-mortem: 152us, LDS-pipe bound (~84us pure LDS occupancy across 16
// waves/CU from 4 serial (b,m) blocks). R9: block = m, covers ALL 4 b
// (a-reads amortized 4x, grid 256 = 1 block/CU, no serial blocks); fp16 LDS
// (x, a half4, Y) halves op widths; Y layout [b][n'][s] pitch 28 makes
// phase-B reads aligned b64 s-quads. Output math stays fp32; /max(X)
// normalization washes fp16 noise (predicted absmax ~5e-3 vs 2e-2).
__global__ __launch_bounds__(256) __attribute__((amdgpu_waves_per_eu(1, 1)))
void cassi_fused(
    const float* __restrict__ x,
    const float* __restrict__ wr, const float* __restrict__ wg,
    const float* __restrict__ wb, const float* __restrict__ wc,
    float* __restrict__ out, float* __restrict__ bmax_out)
{
    extern __shared__ char lds_raw[];
    h4*       A4  = reinterpret_cast<h4*>(lds_raw);
    _Float16* XTh = reinterpret_cast<_Float16*>(lds_raw);   // + XT_OFF_H
    h4*       Y4  = reinterpret_cast<h4*>(lds_raw);         // + Y_OFF_H4
    float*    wmax = reinterpret_cast<float*>(lds_raw + WMAX_OFF);

    const int t = threadIdx.x;
    const int m = blockIdx.x;

    // ---- Staging (once per block) ----
    // zero pad rows s=22,23 of a4h
    for (int j = t; j < 2 * AP_; j += 256) {
        h4 z; z.x = z.y = z.z = z.w = (_Float16)0.f;
        A4[S_ * AP_ + j] = z;
    }
    // x rows for all 4 b (coalesced float4 global), fp16 into [b][n][l] pitch 25
    #pragma unroll
    for (int b = 0; b < B_; ++b) {
        const float4* x4 = reinterpret_cast<const float4*>(x + ((b * M_ + m) * N_ + t) * L_);
        _Float16* row = XTh + XT_OFF_H + (b * N_ + t) * XP_;
        #pragma unroll
        for (int i = 0; i < 6; ++i) {
            const float4 v = x4[i];
            row[4 * i + 0] = (_Float16)v.x;
            row[4 * i + 1] = (_Float16)v.y;
            row[4 * i + 2] = (_Float16)v.z;
            row[4 * i + 3] = (_Float16)v.w;
        }
    }
    // weights: coalesced, normalized once, half4-packed a4h[s][n]
    {
        const float* wrm = wr + m * (N_ * S_);
        const float* wgm = wg + m * (N_ * S_);
        const float* wbm = wb + m * (N_ * S_);
        const float* wcm = wc + m * (N_ * S_);
        #pragma unroll 1
        for (int i = 0; i < S_; ++i) {       // 22*256 = 5632 floats per array
            const int f = i * 256 + t;
            const float r = wrm[f], g = wgm[f], u = wbm[f], v = wcm[f];
            const int n = f / S_, s = f - n * S_;
            const float inv = 1.f / (r + g + u + v);
            h4 p;
            p.x = (_Float16)(r * inv); p.y = (_Float16)(g * inv);
            p.z = (_Float16)(u * inv); p.w = (_Float16)(v * inv);
            A4[s * AP_ + n] = p;
        }
    }
    __syncthreads();

    // ---- Phase A: gather Y[b][n'][s] = sum_l G(n'-l,l,s)*x[b,n'-l,l], s in quads.
    // Lane t: main n'=t (l<=t) + tail n'=256+t (l>t, only t<23) via complementarity;
    // mask folded into G (Gm/Gt) so the b-loop is pure FMA.
    #pragma unroll 1
    for (int i = 0; i < 6; ++i) {
        const int s0 = 4 * i;
        float4 aM[4], aT[4];
        #pragma unroll
        for (int b = 0; b < 4; ++b) { aM[b].x=aM[b].y=aM[b].z=aM[b].w=0.f; aT[b]=aM[b]; }
        #pragma unroll
        for (int l = 0; l < L_; ++l) {
            const bool mn = (l <= t);
            const int idx = mn ? (t - l) : (256 + t - l);
            const float mm = mn ? 1.f : 0.f;
            const int ab = s0 * AP_ + idx;
            const h4 p0 = A4[ab], p1 = A4[ab + AP_], p2 = A4[ab + 2 * AP_], p3 = A4[ab + 3 * AP_];
            const float g0 = (float)p0.x*FR[l] + (float)p0.y*FG[l] + (float)p0.z*FB[l] + (float)p0.w*FC[l];
            const float g1 = (float)p1.x*FR[l] + (float)p1.y*FG[l] + (float)p1.z*FB[l] + (float)p1.w*FC[l];
            const float g2 = (float)p2.x*FR[l] + (float)p2.y*FG[l] + (float)p2.z*FB[l] + (float)p2.w*FC[l];
            const float g3 = (float)p3.x*FR[l] + (float)p3.y*FG[l] + (float)p3.z*FB[l] + (float)p3.w*FC[l];
            const float gm0 = g0 * mm, gt0 = g0 - gm0;
            const float gm1 = g1 * mm, gt1 = g1 - gm1;
            const float gm2 = g2 * mm, gt2 = g2 - gm2;
            const float gm3 = g3 * mm, gt3 = g3 - gm3;
            #pragma unroll
            for (int b = 0; b < 4; ++b) {
                const float xv = (float)XTh[XT_OFF_H + (b * N_ + idx) * XP_ + l];
                aM[b].x += gm0 * xv; aT[b].x += gt0 * xv;
                aM[b].y += gm1 * xv; aT[b].y += gt1 * xv;
                aM[b].z += gm2 * xv; aT[b].z += gt2 * xv;
                aM[b].w += gm3 * xv; aT[b].w += gt3 * xv;
            }
        }
        #pragma unroll
        for (int b = 0; b < 4; ++b) {
            h4 pm;
            pm.x = (_Float16)aM[b].x; pm.y = (_Float16)aM[b].y;
            pm.z = (_Float16)aM[b].z; pm.w = (_Float16)aM[b].w;
            Y4[Y_OFF_H4 + (b * NYR_ + t) * (YPH_ / 4) + i] = pm;
            if (t < 23) {
                h4 pt;
                pt.x = (_Float16)aT[b].x; pt.y = (_Float16)aT[b].y;
                pt.z = (_Float16)aT[b].z; pt.w = (_Float16)aT[b].w;
                Y4[Y_OFF_H4 + (b * NYR_ + 256 + t) * (YPH_ / 4) + i] = pt;
            }
        }
    }
    __syncthreads();

    // ---- Phase B: X[b,t,l] = sum_s G(t,l,s)*Y[b,t+l,s], s-quads via aligned b64.
    float vmax = 0.f;
    #pragma unroll 1
    for (int b = 0; b < 4; ++b) {
        float X[L_];
        #pragma unroll
        for (int l = 0; l < L_; ++l) X[l] = 0.f;
        #pragma unroll 1
        for (int sq = 0; sq < 6; ++sq) {
            const int ab = (4 * sq) * AP_ + t;
            const h4 q0 = A4[ab], q1 = A4[ab + AP_], q2 = A4[ab + 2 * AP_], q3 = A4[ab + 3 * AP_];
            const float a00=(float)q0.x, a01=(float)q0.y, a02=(float)q0.z, a03=(float)q0.w;
            const float a10=(float)q1.x, a11=(float)q1.y, a12=(float)q1.z, a13=(float)q1.w;
            const float a20=(float)q2.x, a21=(float)q2.y, a22=(float)q2.z, a23=(float)q2.w;
            const float a30=(float)q3.x, a31=(float)q3.y, a32=(float)q3.z, a33=(float)q3.w;
            const int yb = Y_OFF_H4 + (b * NYR_ + t) * (YPH_ / 4) + sq;
            #pragma unroll
            for (int l = 0; l < L_; ++l) {
                const h4 y = Y4[yb + 7 * l];
                const float G0 = a00*FR[l] + a01*FG[l] + a02*FB[l] + a03*FC[l];
                const float G1 = a10*FR[l] + a11*FG[l] + a12*FB[l] + a13*FC[l];
                const float G2 = a20*FR[l] + a21*FG[l] + a22*FB[l] + a23*FC[l];
                const float G3 = a30*FR[l] + a31*FG[l] + a32*FB[l] + a33*FC[l];
                X[l] += G0*(float)y.x + G1*(float)y.y + G2*(float)y.z + G3*(float)y.w;
            }
        }
        float4* o4 = reinterpret_cast<float4*>(out + ((b * M_ + m) * N_ + t) * L_);
        #pragma unroll
        for (int i2 = 0; i2 < 6; ++i2) {
            float4 vq;
            vq.x = X[4*i2+0]; vq.y = X[4*i2+1]; vq.z = X[4*i2+2]; vq.w = X[4*i2+3];
            vmax = fmaxf(vmax, fmaxf(fmaxf(vq.x, vq.y), fmaxf(vq.z, vq.w)));
            o4[i2] = vq;
        }
    }

    // per-block max -> bmax_out[m] (256 entries; norm kernel re-reduces)
    #pragma unroll
    for (int off = 32; off > 0; off >>= 1)
        vmax = fmaxf(vmax, __shfl_xor(vmax, off, 64));
    if ((t & 63) == 0) wmax[t >> 6] = vmax;
    __syncthreads();
    if (t == 0)
        bmax_out[m] = fmaxf(fmaxf(wmax[0], wmax[1]), fmaxf(wmax[2], wmax[3]));
}

// Normalize; each block re-reduces the 256 per-block maxes itself (kills the
// separate 1-block reduce launch; +4KB reads/block ~ 1us total).
__global__ __launch_bounds__(256) void cassi_norm(float* __restrict__ out,
                                                  const float* __restrict__ bmax)
{
    __shared__ float wm[4];
    const int t = threadIdx.x;
    float v = bmax[t];
    #pragma unroll
    for (int off = 32; off > 0; off >>= 1)
        v = fmaxf(v, __shfl_xor(v, off, 64));
    if ((t & 63) == 0) wm[t >> 6] = v;
    __syncthreads();
    const float inv = 1.f / fmaxf(fmaxf(wm[0], wm[1]), fmaxf(wm[2], wm[3]));
    const int i = (blockIdx.x * 256 + t) * 4;
    float4 q = *reinterpret_cast<float4*>(out + i);
    q.x *= inv; q.y *= inv; q.z *= inv; q.w *= inv;
    *reinterpret_cast<float4*>(out + i) = q;
}

extern "C" void kernel_launch(void* const* d_in, const int* in_sizes, int n_in,
                              void* d_out, int out_size, void* d_ws, size_t ws_size,
                              hipStream_t stream) {
    const float* x  = (const float*)d_in[0];
    const float* wr = (const float*)d_in[1];
    const float* wg = (const float*)d_in[2];
    const float* wb = (const float*)d_in[3];
    const float* wc = (const float*)d_in[4];
    float* out  = (float*)d_out;
    float* bmax = (float*)d_ws;          // 256 per-block maxes

    // >64KB dynamic LDS opt-in (host-side attribute; capture-safe per R8)
    hipFuncSetAttribute((const void*)cassi_fused,
                        hipFuncAttributeMaxDynamicSharedMemorySize, LDS_BYTES);

    cassi_fused<<<M_, 256, LDS_BYTES, stream>>>(x, wr, wg, wb, wc, out, bmax);
    const int n4blocks = (B_ * M_ * N_ * L_) / 4 / 256;     // 6144, exact
    cassi_norm<<<n4blocks, 256, 0, stream>>>(out, bmax);
}